// Round 3
// baseline (782.807 us; speedup 1.0000x reference)
//
#include <hip/hip_runtime.h>

#define CHN 6
#define NN 65536
#define BB 32
#define NMODES 16

// ---------------- Kernel 1: fused RK4 ODE ----------------
// block = 512 threads, 2 contiguous points/thread -> 1024-pt extended tile,
// 28-pt halo each side (28 dyn evals each shrink validity by 1), central 968.
// P1=2 keeps per-thread RK4 state (u,s,acc,k = 48 floats) within ~80 VGPRs:
// R2 showed P1=4 (96-float state) at VGPR_Count=80 was register-churning
// (~2x dynamic instruction count vs the FMA floor).
#define T1 512
#define P1 2
#define EXT1 (T1*P1)            // 1024
#define HALO1 28
#define TILE1 (EXT1 - 2*HALO1)  // 968
#define NTILES ((NN + TILE1 - 1) / TILE1)  // 68

__device__ __forceinline__ float fast_tanhf(float x){
    // tanh(x) = 1 - 2/(exp(2x)+1); exp(2x) = 2^(x*2*log2(e))
    float e = __builtin_amdgcn_exp2f(x * 2.885390081777926815f);
    float r = __builtin_amdgcn_rcpf(e + 1.0f);
    return 1.0f - 2.0f * r;
}

// __launch_bounds__(512,4): >=4 waves/EU -> VGPR cap 128 (state fits), and
// 2 blocks/CU resident (LDS 48KB/block) = 16 waves/CU.
__global__ __launch_bounds__(512, 4)
void ode_kernel(const float* __restrict__ u0,
                const float* __restrict__ tspan,
                const float* __restrict__ cw,
                const float* __restrict__ cb,
                float* __restrict__ uout)
{
    // double-buffered edge-exchange arrays (first/last point of each thread's pair)
    __shared__ float eF[2][CHN][T1];
    __shared__ float eL[2][CHN][T1];

    const int t = threadIdx.x;
    const int tile = blockIdx.x;
    const int b = blockIdx.y;
    const int j0 = tile*TILE1 - HALO1 + t*P1;     // global index of this thread's pair
    // pairs are 2-aligned and N%2==0 -> pair wholly in or out of domain
    const float m = (j0 >= 0 && j0 < NN) ? 1.0f : 0.0f;

    float u[CHN][P1], s[CHN][P1], acc[CHN][P1], k[CHN][P1];

    #pragma unroll
    for (int c=0;c<CHN;c++){
        float2 v = make_float2(0.f,0.f);
        if (m != 0.0f) v = *(const float2*)(u0 + ((size_t)(b*CHN+c))*NN + j0);
        u[c][0]=v.x; u[c][1]=v.y;
        s[c][0]=v.x; s[c][1]=v.y;
    }

    int buf = 0;
    for (int st=0; st<7; ++st){
        float dt  = tspan[st+1] - tspan[st];
        float hdt = 0.5f*dt;
        float dt6 = dt*(1.0f/6.0f);
        #pragma unroll
        for (int stage=0; stage<4; ++stage){
            // publish edges of current stage input s
            #pragma unroll
            for (int c=0;c<CHN;c++){ eF[buf][c][t]=s[c][0]; eL[buf][c][t]=s[c][1]; }
            __syncthreads();
            const int tl = (t==0)?0:(t-1);
            const int tr = (t==T1-1)?(T1-1):(t+1);
            float vL[CHN], vR[CHN];
            #pragma unroll
            for (int c=0;c<CHN;c++){ vL[c]=eL[buf][c][tl]; vR[c]=eF[buf][c][tr]; }
            buf ^= 1;

            // conv1d k=3 (cross-correlation, zero pad), channels 6->6, + bias.
            // Explicit fmaf chains: 108 FMA/point, no mul+add splits.
            #pragma unroll
            for (int o=0;o<CHN;o++){
                float bo = cb[o];
                k[o][0] = bo; k[o][1] = bo;
            }
            #pragma unroll
            for (int i=0;i<CHN;i++){
                float a0=vL[i], b0=s[i][0], b1=s[i][1], a2=vR[i];
                #pragma unroll
                for (int o=0;o<CHN;o++){
                    float w0=cw[(o*CHN+i)*3+0];
                    float w1=cw[(o*CHN+i)*3+1];
                    float w2=cw[(o*CHN+i)*3+2];
                    k[o][0] = fmaf(w0,a0, fmaf(w1,b0, fmaf(w2,b1, k[o][0])));
                    k[o][1] = fmaf(w0,b0, fmaf(w1,b1, fmaf(w2,a2, k[o][1])));
                }
            }
            #pragma unroll
            for (int o=0;o<CHN;o++){
                k[o][0] = fast_tanhf(k[o][0]);
                k[o][1] = fast_tanhf(k[o][1]);
            }

            // RK4 stage update (m zeroes out-of-domain points -> correct zero padding)
            if (stage==0){
                #pragma unroll
                for (int c=0;c<CHN;c++)
                    #pragma unroll
                    for (int j=0;j<P1;j++){
                        acc[c][j] = k[c][j];
                        s[c][j] = m*fmaf(hdt, k[c][j], u[c][j]);
                    }
            } else if (stage==1){
                #pragma unroll
                for (int c=0;c<CHN;c++)
                    #pragma unroll
                    for (int j=0;j<P1;j++){
                        acc[c][j] = fmaf(2.0f, k[c][j], acc[c][j]);
                        s[c][j] = m*fmaf(hdt, k[c][j], u[c][j]);
                    }
            } else if (stage==2){
                #pragma unroll
                for (int c=0;c<CHN;c++)
                    #pragma unroll
                    for (int j=0;j<P1;j++){
                        acc[c][j] = fmaf(2.0f, k[c][j], acc[c][j]);
                        s[c][j] = m*fmaf(dt, k[c][j], u[c][j]);
                    }
            } else {
                #pragma unroll
                for (int c=0;c<CHN;c++)
                    #pragma unroll
                    for (int j=0;j<P1;j++){
                        u[c][j] = m*fmaf(dt6, acc[c][j] + k[c][j], u[c][j]);
                        s[c][j] = u[c][j];
                    }
            }
        }
    }

    // store central region [HALO1, EXT1-HALO1) -> threads 14..497, clip to N
    if (t >= HALO1/P1 && t < (EXT1-HALO1)/P1 && j0 < NN){
        #pragma unroll
        for (int c=0;c<CHN;c++){
            float2 v = make_float2(u[c][0],u[c][1]);
            *(float2*)(uout + ((size_t)(b*CHN+c))*NN + j0) = v;
        }
    }
}

// ---------------- Kernel 2: partial 16-mode DFT ----------------
// grid (B*CHN, 8 chunks), block 256. Accumulate S_re[k]=sum u*cos, S_im[k]=sum u*sin.
#define DFT_CHUNKS 8
__global__ void dft_kernel(const float* __restrict__ u, float* __restrict__ partial)
{
    const int gx = blockIdx.x;          // b*CHN + c
    const int chunk = blockIdx.y;
    const int t = threadIdx.x;
    const float* up = u + (size_t)gx*NN;

    float are[NMODES], aim[NMODES];
    #pragma unroll
    for (int k2=0;k2<NMODES;k2++){ are[k2]=0.f; aim[k2]=0.f; }

    for (int it=0; it<NN/DFT_CHUNKS/256; ++it){
        int j = chunk*(NN/DFT_CHUNKS) + it*256 + t;
        float v = up[j];
        float rev = (float)j * (1.0f/65536.0f);     // exact (pow2 divisor)
        float c1 = __builtin_amdgcn_cosf(rev);      // hw: cos(2*pi*rev)
        float s1 = __builtin_amdgcn_sinf(rev);
        are[0] += v;
        float ck=c1, sk=s1;
        #pragma unroll
        for (int k2=1;k2<NMODES;k2++){
            are[k2] = fmaf(v,ck,are[k2]);
            aim[k2] = fmaf(v,sk,aim[k2]);
            float cn = fmaf(ck,c1,-sk*s1);
            sk = fmaf(sk,c1, ck*s1);
            ck = cn;
        }
    }
    // wave (64-lane) butterfly reduction
    #pragma unroll
    for (int k2=0;k2<NMODES;k2++){
        for (int off=32; off; off>>=1){
            are[k2] += __shfl_down(are[k2], off, 64);
            aim[k2] += __shfl_down(aim[k2], off, 64);
        }
    }
    __shared__ float red[4][2*NMODES];
    const int wave = t>>6, lane = t&63;
    if (lane==0){
        #pragma unroll
        for (int k2=0;k2<NMODES;k2++){ red[wave][k2]=are[k2]; red[wave][NMODES+k2]=aim[k2]; }
    }
    __syncthreads();
    if (t < 2*NMODES){
        float sum = red[0][t]+red[1][t]+red[2][t]+red[3][t];
        partial[((size_t)gx*DFT_CHUNKS + chunk)*(2*NMODES) + t] = sum;
    }
}

// ---------------- Kernel 3: mix + projection fold (tiny) ----------------
// fin[b,p,k] = sum_i x_ft[b,i,k] * (sum_o proj_w[p,o]*W[i,o,k]),  x_ft = S_re - i*S_im
// coeffs for synthesis: dc = Re(fin0)/N + proj_b ; Cre = 2/N*Re(fin_k) ; Cim = -2/N*Im(fin_k)
__global__ void mix_kernel(const float* __restrict__ partial,
                           const float* __restrict__ sw_r,
                           const float* __restrict__ sw_i,
                           const float* __restrict__ proj_w,
                           const float* __restrict__ proj_b,
                           float* __restrict__ dc,
                           float* __restrict__ cre,
                           float* __restrict__ cim)
{
    int idx = blockIdx.x*256 + threadIdx.x;
    if (idx >= BB*CHN*NMODES) return;
    int k = idx & (NMODES-1);
    int p = (idx >> 4) % CHN;
    int b = idx / (CHN*NMODES);

    float fr = 0.f, fi = 0.f;
    for (int i=0;i<CHN;i++){
        float sre=0.f, sim=0.f;
        for (int c2=0;c2<DFT_CHUNKS;c2++){
            const float* pp = partial + ((size_t)(b*CHN+i)*DFT_CHUNKS + c2)*(2*NMODES);
            sre += pp[k];
            sim += pp[NMODES+k];
        }
        float wpr=0.f, wpi=0.f;
        for (int o=0;o<CHN;o++){
            float pw = proj_w[p*CHN+o];
            wpr += pw * sw_r[((size_t)i*CHN+o)*NMODES + k];
            wpi += pw * sw_i[((size_t)i*CHN+o)*NMODES + k];
        }
        // (sre - i*sim)*(wpr + i*wpi)
        fr += sre*wpr + sim*wpi;
        fi += sre*wpi - sim*wpr;
    }
    const float invN = 1.0f/(float)NN;
    int bp = b*CHN + p;
    if (k==0) dc[bp] = fr*invN + proj_b[p];
    cre[bp*NMODES + k] =  2.0f*invN*fr;
    cim[bp*NMODES + k] = -2.0f*invN*fi;
}

// ---------------- Kernel 4: 16-mode synthesis ----------------
// out[b,p,j] = dc + sum_{k=1..15} Cre[k]*cos(2*pi*k*j/N) + Cim[k]*sin(2*pi*k*j/N)
__global__ void synth_kernel(const float* __restrict__ dc,
                             const float* __restrict__ cre,
                             const float* __restrict__ cim,
                             float* __restrict__ out)
{
    const int bp = blockIdx.x;       // b*CHN + p
    const int chunk = blockIdx.y;
    const int t = threadIdx.x;
    float dcv = dc[bp];
    float cr[NMODES], ci[NMODES];
    #pragma unroll
    for (int k2=1;k2<NMODES;k2++){ cr[k2]=cre[bp*NMODES+k2]; ci[k2]=cim[bp*NMODES+k2]; }

    float* op = out + (size_t)bp*NN;
    for (int it=0; it<NN/DFT_CHUNKS/256; ++it){
        int j = chunk*(NN/DFT_CHUNKS) + it*256 + t;
        float rev = (float)j * (1.0f/65536.0f);
        float c1 = __builtin_amdgcn_cosf(rev);
        float s1 = __builtin_amdgcn_sinf(rev);
        float acc = dcv;
        float ck=c1, sk=s1;
        #pragma unroll
        for (int k2=1;k2<NMODES;k2++){
            acc = fmaf(cr[k2],ck,acc);
            acc = fmaf(ci[k2],sk,acc);
            float cn = fmaf(ck,c1,-sk*s1);
            sk = fmaf(sk,c1, ck*s1);
            ck = cn;
        }
        op[j] = acc;
    }
}

extern "C" void kernel_launch(void* const* d_in, const int* in_sizes, int n_in,
                              void* d_out, int out_size, void* d_ws, size_t ws_size,
                              hipStream_t stream) {
    const float* u0     = (const float*)d_in[0];
    const float* tspan  = (const float*)d_in[1];
    const float* conv_w = (const float*)d_in[2];
    const float* conv_b = (const float*)d_in[3];
    const float* sw_r   = (const float*)d_in[4];
    const float* sw_i   = (const float*)d_in[5];
    const float* proj_w = (const float*)d_in[6];
    const float* proj_b = (const float*)d_in[7];
    float* out = (float*)d_out;

    // ws layout (floats): dc[192] | cre[3072] | cim[3072] | pad | partial[49152]
    float* wsf = (float*)d_ws;
    float* dc      = wsf;
    float* cre     = wsf + 192;
    float* cim     = wsf + 192 + 3072;
    float* partial = wsf + 8192;

    // K1: fused RK4 ODE -> u_final staged in d_out (exactly B*CHN*NN floats)
    ode_kernel<<<dim3(NTILES, BB), T1, 0, stream>>>(u0, tspan, conv_w, conv_b, out);
    // K2: 16-mode partial DFT of u_final
    dft_kernel<<<dim3(BB*CHN, DFT_CHUNKS), 256, 0, stream>>>(out, partial);
    // K3: chunk-sum + spectral mix + projection fold -> synthesis coeffs
    mix_kernel<<<dim3((BB*CHN*NMODES + 255)/256), 256, 0, stream>>>(
        partial, sw_r, sw_i, proj_w, proj_b, dc, cre, cim);
    // K4: synthesis overwrites d_out with final output
    synth_kernel<<<dim3(BB*CHN, DFT_CHUNKS), 256, 0, stream>>>(dc, cre, cim, out);
}

// Round 4
// 442.469 us; speedup vs baseline: 1.7692x; 1.7692x over previous
//
#include <hip/hip_runtime.h>

#define CHN 6
#define NN 65536
#define BB 32
#define NMODES 16

// ---------------- Kernel 1: fused RK4 ODE ----------------
// block = 256 threads, 4 contiguous points/thread -> 1024-pt extended tile,
// 28-pt halo each side (28 dyn evals each shrink validity by 1), central 968.
#define T1 256
#define P1 4
#define EXT1 (T1*P1)            // 1024
#define HALO1 28
#define TILE1 (EXT1 - 2*HALO1)  // 968
#define NTILES ((NN + TILE1 - 1) / TILE1)  // 68

__device__ __forceinline__ float fast_tanhf(float x){
    // tanh(x) = 1 - 2/(exp(2x)+1); exp(2x) = 2^(x*2*log2(e))
    float e = __builtin_amdgcn_exp2f(x * 2.885390081777926815f);
    float r = __builtin_amdgcn_rcpf(e + 1.0f);
    return 1.0f - 2.0f * r;
}

// Register-allocation history on this kernel:
//  R1 no bounds        -> VGPR 64, spill to HBM (WRITE 468MB), 416us
//  R2 launch_bounds(256,2) -> VGPR 80, AGPR/remat churn, 352us
//  R3 launch_bounds(512,4) -> VGPR 40, massive churn, 672us
// The scheduler's occupancy TARGET (not the cap) drives allocation. Pin it:
// waves_per_eu(3,4) -> VGPR budget 512/3 ~= 168, state needs ~120-140.
__global__ __launch_bounds__(256) __attribute__((amdgpu_waves_per_eu(3, 4)))
void ode_kernel(const float* __restrict__ u0,
                const float* __restrict__ tspan,
                const float* __restrict__ cw,
                const float* __restrict__ cb,
                float* __restrict__ uout)
{
    // double-buffered edge-exchange arrays (first/last point of each thread's chunk)
    __shared__ float eF[2][CHN][T1];
    __shared__ float eL[2][CHN][T1];

    const int t = threadIdx.x;
    const int tile = blockIdx.x;
    const int b = blockIdx.y;
    const int j0 = tile*TILE1 - HALO1 + t*P1;     // global index of this thread's chunk
    // chunks are 4-aligned and N%4==0 -> chunk wholly in or out of domain
    const float m = (j0 >= 0 && j0 < NN) ? 1.0f : 0.0f;

    float u[CHN][P1], s[CHN][P1], acc[CHN][P1], k[CHN][P1];

    #pragma unroll
    for (int c=0;c<CHN;c++){
        float4 v = make_float4(0.f,0.f,0.f,0.f);
        if (m != 0.0f) v = *(const float4*)(u0 + ((size_t)(b*CHN+c))*NN + j0);
        u[c][0]=v.x; u[c][1]=v.y; u[c][2]=v.z; u[c][3]=v.w;
        s[c][0]=v.x; s[c][1]=v.y; s[c][2]=v.z; s[c][3]=v.w;
    }

    int buf = 0;
    for (int st=0; st<7; ++st){
        float dt  = tspan[st+1] - tspan[st];
        float hdt = 0.5f*dt;
        float dt6 = dt*(1.0f/6.0f);
        #pragma unroll
        for (int stage=0; stage<4; ++stage){
            // publish edges of current stage input s. Masking HERE (12 muls)
            // implements domain zero-padding: out-of-domain threads' private
            // state may drift (bounded: tanh<=1) but is never stored and its
            // only influence on valid points is via these published edges.
            #pragma unroll
            for (int c=0;c<CHN;c++){ eF[buf][c][t]=m*s[c][0]; eL[buf][c][t]=m*s[c][P1-1]; }
            __syncthreads();
            const int tl = (t==0)?0:(t-1);
            const int tr = (t==T1-1)?(T1-1):(t+1);
            float vL[CHN], vR[CHN];
            #pragma unroll
            for (int c=0;c<CHN;c++){ vL[c]=eL[buf][c][tl]; vR[c]=eF[buf][c][tr]; }
            buf ^= 1;

            // conv1d k=3 (cross-correlation, zero pad), channels 6->6, + bias.
            #pragma unroll
            for (int o=0;o<CHN;o++){
                float bo = cb[o];
                #pragma unroll
                for (int j=0;j<P1;j++) k[o][j] = bo;
            }
            #pragma unroll
            for (int i=0;i<CHN;i++){
                float a0=vL[i], b0=s[i][0], b1=s[i][1], b2=s[i][2], b3=s[i][3], a4=vR[i];
                #pragma unroll
                for (int o=0;o<CHN;o++){
                    float w0=cw[(o*CHN+i)*3+0];
                    float w1=cw[(o*CHN+i)*3+1];
                    float w2=cw[(o*CHN+i)*3+2];
                    k[o][0] = fmaf(w0,a0, fmaf(w1,b0, fmaf(w2,b1, k[o][0])));
                    k[o][1] = fmaf(w0,b0, fmaf(w1,b1, fmaf(w2,b2, k[o][1])));
                    k[o][2] = fmaf(w0,b1, fmaf(w1,b2, fmaf(w2,b3, k[o][2])));
                    k[o][3] = fmaf(w0,b2, fmaf(w1,b3, fmaf(w2,a4, k[o][3])));
                }
            }
            #pragma unroll
            for (int o=0;o<CHN;o++)
                #pragma unroll
                for (int j=0;j<P1;j++)
                    k[o][j] = fast_tanhf(k[o][j]);

            // RK4 stage update (no masking needed; see edge-publish note)
            if (stage==0){
                #pragma unroll
                for (int c=0;c<CHN;c++)
                    #pragma unroll
                    for (int j=0;j<P1;j++){
                        acc[c][j] = k[c][j];
                        s[c][j] = fmaf(hdt, k[c][j], u[c][j]);
                    }
            } else if (stage==1){
                #pragma unroll
                for (int c=0;c<CHN;c++)
                    #pragma unroll
                    for (int j=0;j<P1;j++){
                        acc[c][j] = fmaf(2.0f, k[c][j], acc[c][j]);
                        s[c][j] = fmaf(hdt, k[c][j], u[c][j]);
                    }
            } else if (stage==2){
                #pragma unroll
                for (int c=0;c<CHN;c++)
                    #pragma unroll
                    for (int j=0;j<P1;j++){
                        acc[c][j] = fmaf(2.0f, k[c][j], acc[c][j]);
                        s[c][j] = fmaf(dt, k[c][j], u[c][j]);
                    }
            } else {
                #pragma unroll
                for (int c=0;c<CHN;c++)
                    #pragma unroll
                    for (int j=0;j<P1;j++){
                        u[c][j] = fmaf(dt6, acc[c][j] + k[c][j], u[c][j]);
                        s[c][j] = u[c][j];
                    }
            }
        }
    }

    // store central region [HALO1, EXT1-HALO1) -> threads 7..248, clip to N
    if (t >= HALO1/P1 && t < (EXT1-HALO1)/P1 && j0 < NN){
        #pragma unroll
        for (int c=0;c<CHN;c++){
            float4 v = make_float4(u[c][0],u[c][1],u[c][2],u[c][3]);
            *(float4*)(uout + ((size_t)(b*CHN+c))*NN + j0) = v;
        }
    }
}

// ---------------- Kernel 2: partial 16-mode DFT, 4-fold time decimation ----
// Points j, j+N/4, j+N/2, j+3N/4 share one twiddle (ck,sk); quarter-period
// phase shifts are compile-time sign/swap patterns over k&3:
//   are[k] += P*ck - Q*sk ; aim[k] += Q*ck + P*sk
//   k%4==0: P=v0+v1+v2+v3, Q=0      k%4==1: P=v0-v2, Q=v1-v3
//   k%4==2: P=v0-v1+v2-v3, Q=0      k%4==3: P=v0-v2, Q=-(v1-v3)
#define DFT_CHUNKS 4
#define N4 (NN/4)
__global__ void dft_kernel(const float* __restrict__ u, float* __restrict__ partial)
{
    const int gx = blockIdx.x;          // b*CHN + c
    const int chunk = blockIdx.y;
    const int t = threadIdx.x;
    const float* up = u + (size_t)gx*NN;

    float are[NMODES], aim[NMODES];
    #pragma unroll
    for (int k2=0;k2<NMODES;k2++){ are[k2]=0.f; aim[k2]=0.f; }

    for (int it=0; it<N4/DFT_CHUNKS/256; ++it){
        int j = chunk*(N4/DFT_CHUNKS) + it*256 + t;   // j in [0, N/4)
        float v0 = up[j];
        float v1 = up[j +   N4];
        float v2 = up[j + 2*N4];
        float v3 = up[j + 3*N4];
        float rev = (float)j * (1.0f/65536.0f);       // exact (pow2 divisor)
        float c1 = __builtin_amdgcn_cosf(rev);        // hw: cos(2*pi*rev)
        float s1 = __builtin_amdgcn_sinf(rev);
        float S   = (v0+v2)+(v1+v3);
        float Alt = (v0+v2)-(v1+v3);
        float D02 = v0-v2;
        float D13 = v1-v3;
        are[0] += S;
        float ck=c1, sk=s1;
        #pragma unroll
        for (int k2=1;k2<NMODES;k2++){
            const int km = k2 & 3;
            float P = (km==0) ? S : (km==2) ? Alt : D02;
            are[k2] = fmaf(P,ck,are[k2]);
            aim[k2] = fmaf(P,sk,aim[k2]);
            if (km==1){ are[k2] = fmaf(-D13,sk,are[k2]); aim[k2] = fmaf( D13,ck,aim[k2]); }
            if (km==3){ are[k2] = fmaf( D13,sk,are[k2]); aim[k2] = fmaf(-D13,ck,aim[k2]); }
            float cn = fmaf(ck,c1,-sk*s1);
            sk = fmaf(sk,c1, ck*s1);
            ck = cn;
        }
    }
    // wave (64-lane) butterfly reduction
    #pragma unroll
    for (int k2=0;k2<NMODES;k2++){
        for (int off=32; off; off>>=1){
            are[k2] += __shfl_down(are[k2], off, 64);
            aim[k2] += __shfl_down(aim[k2], off, 64);
        }
    }
    __shared__ float red[4][2*NMODES];
    const int wave = t>>6, lane = t&63;
    if (lane==0){
        #pragma unroll
        for (int k2=0;k2<NMODES;k2++){ red[wave][k2]=are[k2]; red[wave][NMODES+k2]=aim[k2]; }
    }
    __syncthreads();
    if (t < 2*NMODES){
        float sum = red[0][t]+red[1][t]+red[2][t]+red[3][t];
        partial[((size_t)gx*DFT_CHUNKS + chunk)*(2*NMODES) + t] = sum;
    }
}

// ---------------- Kernel 3: mix + projection fold (tiny) ----------------
// fin[b,p,k] = sum_i x_ft[b,i,k] * (sum_o proj_w[p,o]*W[i,o,k]),  x_ft = S_re - i*S_im
// coeffs for synthesis: dc = Re(fin0)/N + proj_b ; Cre = 2/N*Re(fin_k) ; Cim = -2/N*Im(fin_k)
__global__ void mix_kernel(const float* __restrict__ partial,
                           const float* __restrict__ sw_r,
                           const float* __restrict__ sw_i,
                           const float* __restrict__ proj_w,
                           const float* __restrict__ proj_b,
                           float* __restrict__ dc,
                           float* __restrict__ cre,
                           float* __restrict__ cim)
{
    int idx = blockIdx.x*256 + threadIdx.x;
    if (idx >= BB*CHN*NMODES) return;
    int k = idx & (NMODES-1);
    int p = (idx >> 4) % CHN;
    int b = idx / (CHN*NMODES);

    float fr = 0.f, fi = 0.f;
    for (int i=0;i<CHN;i++){
        float sre=0.f, sim=0.f;
        for (int c2=0;c2<DFT_CHUNKS;c2++){
            const float* pp = partial + ((size_t)(b*CHN+i)*DFT_CHUNKS + c2)*(2*NMODES);
            sre += pp[k];
            sim += pp[NMODES+k];
        }
        float wpr=0.f, wpi=0.f;
        for (int o=0;o<CHN;o++){
            float pw = proj_w[p*CHN+o];
            wpr += pw * sw_r[((size_t)i*CHN+o)*NMODES + k];
            wpi += pw * sw_i[((size_t)i*CHN+o)*NMODES + k];
        }
        // (sre - i*sim)*(wpr + i*wpi)
        fr += sre*wpr + sim*wpi;
        fi += sre*wpi - sim*wpr;
    }
    const float invN = 1.0f/(float)NN;
    int bp = b*CHN + p;
    if (k==0) dc[bp] = fr*invN + proj_b[p];
    cre[bp*NMODES + k] =  2.0f*invN*fr;
    cim[bp*NMODES + k] = -2.0f*invN*fi;
}

// ---------------- Kernel 4: 16-mode synthesis, 4-fold decimation ---------
// out[j+m*N/4] = dc + sum_k Cre*cos(theta+phi_km) + Cim*sin(theta+phi_km)
//             = dc + sum_k ck*(Cre*c_phi + Cim*s_phi) + sk*(Cim*c_phi - Cre*s_phi)
// with (c_phi,s_phi) in {0,+-1} per (k&3, m).
__global__ void synth_kernel(const float* __restrict__ dc,
                             const float* __restrict__ cre,
                             const float* __restrict__ cim,
                             float* __restrict__ out)
{
    const int bp = blockIdx.x;       // b*CHN + p
    const int chunk = blockIdx.y;
    const int t = threadIdx.x;
    float dcv = dc[bp];
    float cr[NMODES], ci[NMODES];
    #pragma unroll
    for (int k2=1;k2<NMODES;k2++){ cr[k2]=cre[bp*NMODES+k2]; ci[k2]=cim[bp*NMODES+k2]; }

    float* op = out + (size_t)bp*NN;
    for (int it=0; it<N4/DFT_CHUNKS/256; ++it){
        int j = chunk*(N4/DFT_CHUNKS) + it*256 + t;   // j in [0, N/4)
        float rev = (float)j * (1.0f/65536.0f);
        float c1 = __builtin_amdgcn_cosf(rev);
        float s1 = __builtin_amdgcn_sinf(rev);
        float a0 = dcv, a1 = dcv, a2 = dcv, a3 = dcv;
        float ck=c1, sk=s1;
        #pragma unroll
        for (int k2=1;k2<NMODES;k2++){
            const int km = k2 & 3;
            float R = cr[k2], I = ci[k2];
            // m=0: phi=0
            a0 = fmaf(R,ck,a0); a0 = fmaf(I,sk,a0);
            // m=1: phi = pi*k/2
            if (km==0){ a1 = fmaf( R,ck,a1); a1 = fmaf( I,sk,a1); }
            if (km==1){ a1 = fmaf( I,ck,a1); a1 = fmaf(-R,sk,a1); }
            if (km==2){ a1 = fmaf(-R,ck,a1); a1 = fmaf(-I,sk,a1); }
            if (km==3){ a1 = fmaf(-I,ck,a1); a1 = fmaf( R,sk,a1); }
            // m=2: phi = pi*k
            if (km==0||km==2){ a2 = fmaf( R,ck,a2); a2 = fmaf( I,sk,a2); }
            else             { a2 = fmaf(-R,ck,a2); a2 = fmaf(-I,sk,a2); }
            // m=3: phi = 3*pi*k/2
            if (km==0){ a3 = fmaf( R,ck,a3); a3 = fmaf( I,sk,a3); }
            if (km==1){ a3 = fmaf(-I,ck,a3); a3 = fmaf( R,sk,a3); }
            if (km==2){ a3 = fmaf(-R,ck,a3); a3 = fmaf(-I,sk,a3); }
            if (km==3){ a3 = fmaf( I,ck,a3); a3 = fmaf(-R,sk,a3); }
            float cn = fmaf(ck,c1,-sk*s1);
            sk = fmaf(sk,c1, ck*s1);
            ck = cn;
        }
        op[j]        = a0;
        op[j +   N4] = a1;
        op[j + 2*N4] = a2;
        op[j + 3*N4] = a3;
    }
}

extern "C" void kernel_launch(void* const* d_in, const int* in_sizes, int n_in,
                              void* d_out, int out_size, void* d_ws, size_t ws_size,
                              hipStream_t stream) {
    const float* u0     = (const float*)d_in[0];
    const float* tspan  = (const float*)d_in[1];
    const float* conv_w = (const float*)d_in[2];
    const float* conv_b = (const float*)d_in[3];
    const float* sw_r   = (const float*)d_in[4];
    const float* sw_i   = (const float*)d_in[5];
    const float* proj_w = (const float*)d_in[6];
    const float* proj_b = (const float*)d_in[7];
    float* out = (float*)d_out;

    // ws layout (floats): dc[192] | cre[3072] | cim[3072] | pad | partial[24576]
    float* wsf = (float*)d_ws;
    float* dc      = wsf;
    float* cre     = wsf + 192;
    float* cim     = wsf + 192 + 3072;
    float* partial = wsf + 8192;

    // K1: fused RK4 ODE -> u_final staged in d_out (exactly B*CHN*NN floats)
    ode_kernel<<<dim3(NTILES, BB), T1, 0, stream>>>(u0, tspan, conv_w, conv_b, out);
    // K2: 16-mode partial DFT of u_final (4-fold decimated)
    dft_kernel<<<dim3(BB*CHN, DFT_CHUNKS), 256, 0, stream>>>(out, partial);
    // K3: chunk-sum + spectral mix + projection fold -> synthesis coeffs
    mix_kernel<<<dim3((BB*CHN*NMODES + 255)/256), 256, 0, stream>>>(
        partial, sw_r, sw_i, proj_w, proj_b, dc, cre, cim);
    // K4: synthesis overwrites d_out with final output (4-fold decimated)
    synth_kernel<<<dim3(BB*CHN, DFT_CHUNKS), 256, 0, stream>>>(dc, cre, cim, out);
}